// Round 1
// baseline (117.162 us; speedup 1.0000x reference)
//
#include <hip/hip_runtime.h>

#define M_BASIS 100
constexpr float INV_TWO_PI = 0.15915494309189535f;

__global__ __launch_bounds__(256) void cs_kernel(
    const float* __restrict__ theta,
    const float* __restrict__ basis_mu,
    const float* __restrict__ basis_sigma,
    float* __restrict__ out,
    int total)
{
    __shared__ float s_mu[2 * M_BASIS];
    __shared__ float s_sig[4 * M_BASIS];
    for (int k = threadIdx.x; k < 2 * M_BASIS; k += blockDim.x) s_mu[k] = basis_mu[k];
    for (int k = threadIdx.x; k < 4 * M_BASIS; k += blockDim.x) s_sig[k] = basis_sigma[k];
    __syncthreads();

    int i = blockIdx.x * blockDim.x + threadIdx.x;
    if (i >= total) return;
    int n = i / M_BASIS;
    int j = i - n * M_BASIS;

    // Per-row: P = -2 * theta[:,2:6]; Sigma = 0.5*(Pinv + Pinv^T); Mu = Sigma @ eta
    const float* th = theta + n * 6;
    float t0 = th[0], t1 = th[1], t2 = th[2], t3 = th[3], t4 = th[4], t5 = th[5];
    float p00 = -2.0f * t2, p01 = -2.0f * t3, p10 = -2.0f * t4, p11 = -2.0f * t5;
    float detP = p00 * p11 - p01 * p10;
    float inv_detP = 1.0f / detP;
    float S00 = p11 * inv_detP;
    float S11 = p00 * inv_detP;
    float S01 = -0.5f * (p01 + p10) * inv_detP;  // symmetrized off-diagonal
    float Mu0 = S00 * t0 + S01 * t1;
    float Mu1 = S01 * t0 + S11 * t1;

    // Per (n,j): C = Sigma + S_j, r = exp(-0.5 * diff^T Cinv diff) / (2*pi*sqrt(detC))
    float c00 = S00 + s_sig[4 * j + 0];
    float c01 = S01 + s_sig[4 * j + 1];
    float c10 = S01 + s_sig[4 * j + 2];
    float c11 = S11 + s_sig[4 * j + 3];
    float d0 = Mu0 - s_mu[2 * j + 0];
    float d1 = Mu1 - s_mu[2 * j + 1];
    float detC = c00 * c11 - c01 * c10;
    float invC = 1.0f / detC;
    // quad = invC * (d0*(c11*d0 - c01*d1) + d1*(c00*d1 - c10*d0))
    float quad = (d0 * (c11 * d0 - c01 * d1) + d1 * (c00 * d1 - c10 * d0)) * invC;
    out[i] = __expf(-0.5f * quad) * INV_TWO_PI * rsqrtf(detC);
}

extern "C" void kernel_launch(void* const* d_in, const int* in_sizes, int n_in,
                              void* d_out, int out_size, void* d_ws, size_t ws_size,
                              hipStream_t stream) {
    const float* theta      = (const float*)d_in[0];   // [N,6]
    const float* basis_mu   = (const float*)d_in[1];   // [M,2]
    const float* basis_sig  = (const float*)d_in[2];   // [M,2,2]
    float* out = (float*)d_out;                        // [N,M]

    int total = out_size;  // N * M
    int block = 256;
    int grid = (total + block - 1) / block;
    hipLaunchKernelGGL(cs_kernel, dim3(grid), dim3(block), 0, stream,
                       theta, basis_mu, basis_sig, out, total);
}

// Round 2
// 87.078 us; speedup vs baseline: 1.3455x; 1.3455x over previous
//
#include <hip/hip_runtime.h>

#define M_BASIS 100
constexpr float INV_TWO_PI = 0.15915494309189535f;

// One wave (64 lanes) per row. Lane owns basis index j0=lane and j1=lane+64.
// Basis params live in registers; theta loads are wave-uniform broadcasts;
// per-row Sigma/Mu computed once per row (amortized over 100 outputs).
__global__ __launch_bounds__(256) void cs_kernel(
    const float* __restrict__ theta,
    const float* __restrict__ basis_mu,
    const float* __restrict__ basis_sigma,
    float* __restrict__ out,
    int N)
{
    const int lane = threadIdx.x & 63;
    const int waves_per_block = blockDim.x >> 6;
    const int wave_id = blockIdx.x * waves_per_block + (threadIdx.x >> 6);
    const int num_waves = gridDim.x * waves_per_block;

    // --- hoist basis params into registers (j0 = lane, j1 = lane + 64) ---
    const int j0 = lane;
    const int j1 = lane + 64;
    const bool has_j1 = (j1 < M_BASIS);

    float2 muA = ((const float2*)basis_mu)[j0];
    float4 sgA = ((const float4*)basis_sigma)[j0];
    float2 muB = make_float2(0.f, 0.f);
    float4 sgB = make_float4(1.f, 0.f, 0.f, 1.f);
    if (has_j1) {
        muB = ((const float2*)basis_mu)[j1];
        sgB = ((const float4*)basis_sigma)[j1];
    }

    for (int n = wave_id; n < N; n += num_waves) {
        const float* th = theta + n * 6;          // 24B-aligned (8B multiple)
        float2 e  = *(const float2*)(th);         // eta0, eta1
        float2 qa = *(const float2*)(th + 2);     // t2, t3
        float2 qb = *(const float2*)(th + 4);     // t4, t5

        // P = -2 * theta[2:6]; Sigma = sym(P^-1); Mu = Sigma @ eta
        float p00 = -2.0f * qa.x, p01 = -2.0f * qa.y;
        float p10 = -2.0f * qb.x, p11 = -2.0f * qb.y;
        float detP = p00 * p11 - p01 * p10;
        float inv_detP = __builtin_amdgcn_rcpf(detP);
        float S00 = p11 * inv_detP;
        float S11 = p00 * inv_detP;
        float S01 = -0.5f * (p01 + p10) * inv_detP;
        float Mu0 = S00 * e.x + S01 * e.y;
        float Mu1 = S01 * e.x + S11 * e.y;

        float* orow = out + (size_t)n * M_BASIS;

        // chunk A: j = lane (all 64 lanes)
        {
            float c00 = S00 + sgA.x, c01 = S01 + sgA.y;
            float c10 = S01 + sgA.z, c11 = S11 + sgA.w;
            float d0 = Mu0 - muA.x, d1 = Mu1 - muA.y;
            float detC = c00 * c11 - c01 * c10;
            float invC = __builtin_amdgcn_rcpf(detC);
            float quad = (d0 * (c11 * d0 - c01 * d1) + d1 * (c00 * d1 - c10 * d0)) * invC;
            orow[j0] = __expf(-0.5f * quad) * INV_TWO_PI * __builtin_amdgcn_rsqf(detC);
        }
        // chunk B: j = lane + 64 (36 active lanes)
        if (has_j1) {
            float c00 = S00 + sgB.x, c01 = S01 + sgB.y;
            float c10 = S01 + sgB.z, c11 = S11 + sgB.w;
            float d0 = Mu0 - muB.x, d1 = Mu1 - muB.y;
            float detC = c00 * c11 - c01 * c10;
            float invC = __builtin_amdgcn_rcpf(detC);
            float quad = (d0 * (c11 * d0 - c01 * d1) + d1 * (c00 * d1 - c10 * d0)) * invC;
            orow[j1] = __expf(-0.5f * quad) * INV_TWO_PI * __builtin_amdgcn_rsqf(detC);
        }
    }
}

extern "C" void kernel_launch(void* const* d_in, const int* in_sizes, int n_in,
                              void* d_out, int out_size, void* d_ws, size_t ws_size,
                              hipStream_t stream) {
    const float* theta      = (const float*)d_in[0];   // [N,6]
    const float* basis_mu   = (const float*)d_in[1];   // [M,2]
    const float* basis_sig  = (const float*)d_in[2];   // [M,2,2]
    float* out = (float*)d_out;                        // [N,M]

    int N = in_sizes[0] / 6;
    // 4096 blocks x 4 waves = 16384 waves -> 8 rows per wave
    int block = 256;
    int grid = 4096;
    hipLaunchKernelGGL(cs_kernel, dim3(grid), dim3(block), 0, stream,
                       theta, basis_mu, basis_sig, out, N);
}